// Round 1
// baseline (448.119 us; speedup 1.0000x reference)
//
#include <hip/hip_runtime.h>

// PointConv (kernel=stride=2x2, pad=0, grouping=C): per-location GEMM
//   out_l(32x256) = P_l(32x256) @ W_l(256x256) + bias[:,l]
// B=32, C=64, H=W=64, nH=nW=32, L=1024, n=256. fp32 in/out, bf16 MFMA inside
// (threshold 2.375e-2 >> bf16 error ~5e-3). Memory-bound: 256MB weight stream.

#define B_  32
#define C_  64
#define H_  64
#define W_  64
#define L_  1024
#define N_  256
#define SA  264   // LDS row stride (elems): 256 + 8 pad -> <=2-way bank aliasing (free)

typedef __bf16 bf16x8 __attribute__((ext_vector_type(8)));
typedef float  f32x4  __attribute__((ext_vector_type(4)));

__device__ __forceinline__ unsigned short f2bf(float f) {
  unsigned int u = __builtin_bit_cast(unsigned int, f);
  u += 0x7FFFu + ((u >> 16) & 1u);          // RNE
  return (unsigned short)(u >> 16);
}

__global__ __launch_bounds__(256, 4) void pointconv_kernel(
    const float* __restrict__ x, const float* __restrict__ wgt,
    const float* __restrict__ bias, float* __restrict__ out) {
  __shared__ unsigned short A[B_ * SA];     // patches, bf16, [b][n]

  const int bid = blockIdx.x;
  // XCD swizzle: blocks on XCD x (bid%8) get contiguous l-range -> the 8 blocks
  // sharing each 64B x/out cache line (consecutive pw) are concurrent on one XCD.
  const int l  = ((bid & 7) << 7) | (bid >> 3);
  const int ph = l >> 5, pw = l & 31;
  const int h0 = ph * 2, w0 = pw * 2;

  const int tid = threadIdx.x;

  // ---- Phase 1: unfold x[b, c, 2ph+kh, 2pw+kw] -> A[b][n = c*4 + kh*2 + kw]
  {
    const int b  = tid & 31;
    const int c0 = tid >> 5;                // 0..7
#pragma unroll
    for (int i = 0; i < 8; ++i) {
      const int c = c0 + i * 8;
      const float* px = x + (((b * C_ + c) * H_ + h0) * W_ + w0);
      float2 v0 = *(const float2*)px;        // (kh=0, kw=0..1)
      float2 v1 = *(const float2*)(px + W_); // (kh=1, kw=0..1)
      ushort4 q;
      q.x = f2bf(v0.x); q.y = f2bf(v0.y);
      q.z = f2bf(v1.x); q.w = f2bf(v1.y);
      *(ushort4*)&A[b * SA + c * 4] = q;
    }
  }
  __syncthreads();

  const int lane = tid & 63;
  const int wv   = tid >> 6;      // wave 0..3, owns p in [wv*64, wv*64+64)
  const int col  = lane & 15;     // MFMA n-col / A m-row
  const int quad = lane >> 4;     // 0..3

  // ---- bias init: acc[mt][nt], C/D layout col=lane&15 (p), row=quad*4+reg (b)
  f32x4 acc[2][4];
#pragma unroll
  for (int nt = 0; nt < 4; ++nt) {
    const int p = wv * 64 + nt * 16 + col;
    const float bv = bias[p * L_ + l];       // bias shape (n, L)
#pragma unroll
    for (int mt = 0; mt < 2; ++mt) {
      acc[mt][nt][0] = bv; acc[mt][nt][1] = bv;
      acc[mt][nt][2] = bv; acc[mt][nt][3] = bv;
    }
  }

  const float* __restrict__ wl = wgt + (size_t)l * (N_ * N_);

  // ---- Phase 2: K-loop, K=256 in 8 steps of 32
#pragma unroll 1
  for (int k0 = 0; k0 < 256; k0 += 32) {
    // A-frags: A[m = mt*16+col][k = k0 + quad*8 + j], one ds_read_b128 each
    bf16x8 af[2];
#pragma unroll
    for (int mt = 0; mt < 2; ++mt)
      af[mt] = *(const bf16x8*)&A[(mt * 16 + col) * SA + k0 + quad * 8];

#pragma unroll
    for (int nt = 0; nt < 4; ++nt) {
      const int p = wv * 64 + nt * 16 + col;
      const float* wp = wl + (k0 + quad * 8) * N_ + p;
      // B-frag: B[k = k0+quad*8+j][n=col] = W_l[k][p]; 8 coalesced dword loads
      union { unsigned short s[8]; bf16x8 v; } bu;
#pragma unroll
      for (int j = 0; j < 8; ++j)
        bu.s[j] = f2bf(wp[j * N_]);
#pragma unroll
      for (int mt = 0; mt < 2; ++mt)
        acc[mt][nt] = __builtin_amdgcn_mfma_f32_16x16x32_bf16(
            af[mt], bu.v, acc[mt][nt], 0, 0, 0);
    }
  }

  // ---- Epilogue: fold. p -> (c = p>>2, kh = (p>>1)&1, kw = p&1)
#pragma unroll
  for (int mt = 0; mt < 2; ++mt) {
#pragma unroll
    for (int nt = 0; nt < 4; ++nt) {
      const int p  = wv * 64 + nt * 16 + col;
      const int c  = p >> 2;
      const int kh = (p >> 1) & 1;
      const int kw = p & 1;
      float* po = out + (((0 * C_ + c) * H_ + h0 + kh) * W_ + w0 + kw);
#pragma unroll
      for (int r = 0; r < 4; ++r) {
        const int b = mt * 16 + quad * 4 + r;
        po[b * (C_ * H_ * W_)] = acc[mt][nt][r];
      }
    }
  }
}

extern "C" void kernel_launch(void* const* d_in, const int* in_sizes, int n_in,
                              void* d_out, int out_size, void* d_ws, size_t ws_size,
                              hipStream_t stream) {
  const float* x    = (const float*)d_in[0];
  const float* wgt  = (const float*)d_in[1];
  const float* bias = (const float*)d_in[2];
  float* out = (float*)d_out;
  pointconv_kernel<<<dim3(L_), dim3(256), 0, stream>>>(x, wgt, bias, out);
}

// Round 2
// 417.666 us; speedup vs baseline: 1.0729x; 1.0729x over previous
//
#include <hip/hip_runtime.h>

// PointConv (kernel=stride=2x2, pad=0, grouping=C): per-location GEMM
//   out_l(32x256) = P_l(32x256) @ W_l(256x256) + bias[:,l]
// B=32, C=64, H=W=64, L=1024, n=256. fp32 in/out, bf16 MFMA inside.
// Memory-bound (256MB weight stream). R1 was latency-bound (VGPR=32 ->
// no MLP on 32 scalar W loads). R2: dwordx4 W loads double-buffered in
// registers -> bf16 LDS slab -> ds_read_u16 B-frags.

#define B_  32
#define C_  64
#define H_  64
#define W_  64
#define L_  1024
#define N_  256
#define SA  264   // A pitch (ushorts): 256+8
#define PW  268   // W slab pitch (ushorts): quad-base spread 16q+6j -> 2-way reads (free)

typedef __bf16 bf16x8 __attribute__((ext_vector_type(8)));
typedef float  f32x4  __attribute__((ext_vector_type(4)));

__device__ __forceinline__ unsigned short f2bf(float f) {
  unsigned int u = __builtin_bit_cast(unsigned int, f);
  u += 0x7FFFu + ((u >> 16) & 1u);          // RNE
  return (unsigned short)(u >> 16);
}

__global__ __launch_bounds__(256, 3) void pointconv_kernel(
    const float* __restrict__ x, const float* __restrict__ wgt,
    const float* __restrict__ bias, float* __restrict__ out) {
  __shared__ unsigned short A[B_ * SA];     // patches bf16 [b][n]
  __shared__ unsigned short WS[32 * PW];    // W k-slab bf16 [kk][p]

  const int bid = blockIdx.x;
  // XCD swizzle: consecutive-pw blocks co-resident on one XCD (x/out L2 merge)
  const int l  = ((bid & 7) << 7) | (bid >> 3);
  const int ph = l >> 5, pw = l & 31;
  const int h0 = ph * 2, w0 = pw * 2;
  const int tid = threadIdx.x;

  const float* __restrict__ wl = wgt + (size_t)l * (N_ * N_);

  // ---- W slab staging map: thread -> rows k=kb..kb+7, cols pq..pq+3 (dwordx4)
  const int kb = (tid >> 6) * 8;
  const int pq = (tid & 63) * 4;
  const float* wbase = wl + kb * N_ + pq;

  f32x4 wreg[8];                            // slab double-buffer (registers)
#pragma unroll
  for (int i = 0; i < 8; ++i)
    wreg[i] = *(const f32x4*)(wbase + i * N_);

  // ---- Phase 1: unfold x[b, c, 2ph+kh, 2pw+kw] -> A[b][n = c*4 + kh*2 + kw]
  {
    const int b  = tid & 31;
    const int c0 = tid >> 5;
#pragma unroll
    for (int i = 0; i < 8; ++i) {
      const int c = c0 + i * 8;
      const float* px = x + (((b * C_ + c) * H_ + h0) * W_ + w0);
      float2 v0 = *(const float2*)px;
      float2 v1 = *(const float2*)(px + W_);
      ushort4 q;
      q.x = f2bf(v0.x); q.y = f2bf(v0.y);
      q.z = f2bf(v1.x); q.w = f2bf(v1.y);
      *(ushort4*)&A[b * SA + c * 4] = q;
    }
  }

  const int lane = tid & 63;
  const int wv   = tid >> 6;      // wave owns p in [wv*64, wv*64+64)
  const int col  = lane & 15;
  const int quad = lane >> 4;

  // ---- bias init (C/D: col=lane&15 -> p, row=quad*4+reg -> b)
  f32x4 acc[2][4];
#pragma unroll
  for (int nt = 0; nt < 4; ++nt) {
    const int p = wv * 64 + nt * 16 + col;
    const float bv = bias[p * L_ + l];
#pragma unroll
    for (int mt = 0; mt < 2; ++mt) {
      acc[mt][nt][0] = bv; acc[mt][nt][1] = bv;
      acc[mt][nt][2] = bv; acc[mt][nt][3] = bv;
    }
  }

  // ---- K-loop: 8 slabs of 32
#pragma unroll 1
  for (int k0 = 0; k0 < N_; k0 += 32) {
    // convert + store current slab (s_waitcnt on wreg loads happens here)
#pragma unroll
    for (int i = 0; i < 8; ++i) {
      ushort4 q;
      q.x = f2bf(wreg[i][0]); q.y = f2bf(wreg[i][1]);
      q.z = f2bf(wreg[i][2]); q.w = f2bf(wreg[i][3]);
      *(ushort4*)&WS[(kb + i) * PW + pq] = q;
    }
    __syncthreads();

    // prefetch next slab -> registers (overlaps LDS reads + MFMA below)
    if (k0 + 32 < N_) {
      const float* nb = wbase + (k0 + 32) * N_;
#pragma unroll
      for (int i = 0; i < 8; ++i)
        wreg[i] = *(const f32x4*)(nb + i * N_);
    }

    // A-frags: A[m=mt*16+col][k = k0 + quad*8 + j] -- ds_read_b128
    bf16x8 af[2];
#pragma unroll
    for (int mt = 0; mt < 2; ++mt)
      af[mt] = *(const bf16x8*)&A[(mt * 16 + col) * SA + k0 + quad * 8];

#pragma unroll
    for (int nt = 0; nt < 4; ++nt) {
      const int p = wv * 64 + nt * 16 + col;
      union { unsigned short s[8]; bf16x8 v; } bu;
#pragma unroll
      for (int j = 0; j < 8; ++j)
        bu.s[j] = WS[(quad * 8 + j) * PW + p];
#pragma unroll
      for (int mt = 0; mt < 2; ++mt)
        acc[mt][nt] = __builtin_amdgcn_mfma_f32_16x16x32_bf16(
            af[mt], bu.v, acc[mt][nt], 0, 0, 0);
    }
    __syncthreads();   // WS reads done before next iter's writes
  }

  // ---- Epilogue: fold. p -> (c=p>>2, kh=(p>>1)&1, kw=p&1)
#pragma unroll
  for (int mt = 0; mt < 2; ++mt) {
#pragma unroll
    for (int nt = 0; nt < 4; ++nt) {
      const int p  = wv * 64 + nt * 16 + col;
      const int c  = p >> 2;
      const int kh = (p >> 1) & 1;
      const int kw = p & 1;
      float* po = out + (((c * H_) + h0 + kh) * W_ + w0 + kw);
#pragma unroll
      for (int r = 0; r < 4; ++r) {
        const int b = mt * 16 + quad * 4 + r;
        po[b * (C_ * H_ * W_)] = acc[mt][nt][r];
      }
    }
  }
}

extern "C" void kernel_launch(void* const* d_in, const int* in_sizes, int n_in,
                              void* d_out, int out_size, void* d_ws, size_t ws_size,
                              hipStream_t stream) {
  const float* x    = (const float*)d_in[0];
  const float* wgt  = (const float*)d_in[1];
  const float* bias = (const float*)d_in[2];
  float* out = (float*)d_out;
  pointconv_kernel<<<dim3(L_), dim3(256), 0, stream>>>(x, wgt, bias, out);
}